// Round 7
// baseline (305.284 us; speedup 1.0000x reference)
//
#include <hip/hip_runtime.h>
#include <math.h>

#define NC 1024
#define NF 16384
#define NPTS (2*NF + 2*NC)   // 34816 packed queries / max-accumulators
#define TPB  256
#define GRID 2176

typedef _Float16 f16x8 __attribute__((ext_vector_type(8)));
typedef float    f32x16 __attribute__((ext_vector_type(16)));

// Order-preserving float -> uint encoding (for atomicMax on floats incl. negatives)
__device__ __forceinline__ unsigned enc_f(float f) {
    unsigned u = __float_as_uint(f);
    return (u & 0x80000000u) ? ~u : (u | 0x80000000u);
}
__device__ __forceinline__ float dec_f(unsigned k) {
    unsigned u = (k & 0x80000000u) ? (k ^ 0x80000000u) : ~k;
    return __uint_as_float(u);
}

// VGPR-form MFMA via inline asm (R6; at worst neutral vs builtin, keeps D/acc
// in arch VGPRs). Literal 0 for C is a legal inline constant (ISA §10).
#define MFMA_V(d, a, b) \
    asm("v_mfma_f32_32x32x16_f16 %0, %1, %2, 0" : "=&v"(d) : "v"(a), "v"(b))

// Packed query-index layout (mm uses it):
//   [0, NF)            : ref_points_f             (pass A queries; B/D targets)
//   [NF, 2NF)          : src_points_f transformed (pass B queries; A/C targets)
//   [2NF, 2NF+NC)      : ref_points_c             (pass C queries)
//   [2NF+NC, 2NF+2NC)  : src_points_c transformed (pass D queries)
struct P3 { float x, y, z; };

__device__ __forceinline__ P3 xform(P3 p, const float* __restrict__ T) {
    P3 r;
    r.x = T[0]*p.x + T[1]*p.y + T[2]*p.z  + T[3];
    r.y = T[4]*p.x + T[5]*p.y + T[6]*p.z  + T[7];
    r.z = T[8]*p.x + T[9]*p.y + T[10]*p.z + T[11];
    return r;
}

// packed index -> world-space point (transform applied for src sets)
__device__ __forceinline__ P3 q_point(int qi,
    const float* __restrict__ refc, const float* __restrict__ srcc,
    const float* __restrict__ reff, const float* __restrict__ srcf,
    const float* __restrict__ T)
{
    const float* p; bool xf;
    if (qi < NF)           { p = reff + 3*qi;            xf = false; }
    else if (qi < 2*NF)    { p = srcf + 3*(qi-NF);       xf = true;  }
    else if (qi < 2*NF+NC) { p = refc + 3*(qi-2*NF);     xf = false; }
    else                   { p = srcc + 3*(qi-2*NF-NC);  xf = true;  }
    P3 q = {p[0], p[1], p[2]};
    return xf ? xform(q, T) : q;
}

// f16 hi/lo split records for MFMA K-packing (K=16) — math proven R2-R6:
//   A rec: k = [qhx qhy qhz | qlx qly qlz | qhx qhy qhz | 1 1 | qlx qly qlz | 0 0]
//   B rec: k = [phx phy phz | phx phy phz | plx ply plz | -hh -hl | plx ply plz | 0 0]
// => sum_k A[k]B[k] = q.p - |p|^2/2 to ~1e-5.
__device__ __forceinline__ f16x8 a_rec(P3 q, int hf) {
    _Float16 hx = (_Float16)q.x, hy = (_Float16)q.y, hz = (_Float16)q.z;
    _Float16 lx = (_Float16)(q.x - (float)hx);
    _Float16 ly = (_Float16)(q.y - (float)hy);
    _Float16 lz = (_Float16)(q.z - (float)hz);
    _Float16 one = (_Float16)1.0f, zz = (_Float16)0.0f;
    return hf ? (f16x8){hz, one, one, lx, ly, lz, zz, zz}
              : (f16x8){hx, hy, hz, lx, ly, lz, hx, hy};
}
__device__ __forceinline__ void b_recs(P3 p, f16x8& r0, f16x8& r1) {
    float h = 0.5f*(p.x*p.x + p.y*p.y + p.z*p.z);
    _Float16 hx = (_Float16)p.x, hy = (_Float16)p.y, hz = (_Float16)p.z;
    _Float16 lx = (_Float16)(p.x - (float)hx);
    _Float16 ly = (_Float16)(p.y - (float)hy);
    _Float16 lz = (_Float16)(p.z - (float)hz);
    _Float16 hh = (_Float16)h;
    _Float16 hl = (_Float16)(h - (float)hh);
    _Float16 zz = (_Float16)0.0f;
    r0 = (f16x8){hx, hy, hz, hx, hy, hz, lx, ly};
    r1 = (f16x8){lz, (_Float16)(-hh), (_Float16)(-hl), lx, ly, lz, zz, zz};
}

// Single fused kernel: per-block record gen -> MFMA min-dist -> atomicMax;
// last-finishing block computes both BCE losses (device-scope atomic reads of
// mm => coherent across XCDs; hq recomputed locally => no stale plain loads).
// Grid 2176: A [0,1024) rb<64  | B [1024,2048) rb<64 | C [2048,2112) rb<4 |
//            D [2112,2176) rb<4;  16 target-chunks each.
__global__ __launch_bounds__(TPB, 4) void minmax_kernel(
    const float* __restrict__ refc, const float* __restrict__ srcc,
    const float* __restrict__ reff, const float* __restrict__ srcf,
    const float* __restrict__ T,
    const float* __restrict__ p2p_ref, const float* __restrict__ p2p_src,
    const float* __restrict__ n2p_ref, const float* __restrict__ n2p_src,
    unsigned* __restrict__ mm, unsigned* __restrict__ done,
    float* __restrict__ out)
{
    // 32KB B-record staging; reused after barrier as 4x8704B transpose scratch
    __shared__ __align__(16) char ldsraw[34816];
    f16x8* sbuf = (f16x8*)ldsraw;
    __shared__ float rc[2][4], rp[2][4], rn[2][4];
    __shared__ int tailflag;

    int b = blockIdx.x;
    int qoff, toff, rb, ck;
    if (b < 1024)      { rb = b >> 4;              ck = b & 15; qoff = 0;          toff = NF; }
    else if (b < 2048) { int bb=b-1024; rb=bb>>4;  ck=bb&15;    qoff = NF;         toff = 0;  }
    else if (b < 2112) { int bb=b-2048; rb=bb>>4;  ck=bb&15;    qoff = 2*NF;       toff = NF; }
    else               { int bb=b-2112; rb=bb>>4;  ck=bb&15;    qoff = 2*NF + NC;  toff = 0;  }
    int rbase = qoff + rb * 256;

    int tid = threadIdx.x, wv = tid >> 6, ln = tid & 63;

    // ---- in-block B-record gen: 4 targets/thread -> LDS (consecutive b128) ----
    const float* tp = (toff == NF) ? srcf : reff;   // raw target coords
    bool txf = (toff == NF);
#pragma unroll
    for (int rr = 0; rr < 4; rr++) {
        int j  = tid + rr * 256;
        int gj = ck * 1024 + j;
        P3 p = {tp[3*gj], tp[3*gj+1], tp[3*gj+2]};
        if (txf) p = xform(p, T);
        f16x8 r0, r1;
        b_recs(p, r0, r1);
        sbuf[j]        = r0;
        sbuf[1024 + j] = r1;
    }

    // ---- in-block A-records: 2 rows/lane, plane hf ----
    int m  = ln & 31;        // A-row within tile / B-col within tile
    int hf = ln >> 5;        // K-group select
    int rA = rbase + wv * 64 + m;
    f16x8 aA = a_rec(q_point(rA,      refc, srcc, reff, srcf, T), hf);
    f16x8 aB = a_rec(q_point(rA + 32, refc, srcc, reff, srcf, T), hf);

    f32x16 acc0, acc1;
#pragma unroll
    for (int r = 0; r < 16; r++) { acc0[r] = -3.0e38f; acc1[r] = -3.0e38f; }

    __syncthreads();

    // ---- main loop: 16 iters x (2 ds_read_b128 + 4 MFMA + 32 v_max3) ----
    const f16x8* sb = sbuf + hf * 1024 + m;
    f16x8 bA = sb[0], bB = sb[32];
    for (int u = 0; u < 16; ++u) {
        f32x16 d0, d1, d2, d3;
        MFMA_V(d0, aA, bA);
        MFMA_V(d1, aA, bB);
        MFMA_V(d2, aB, bA);
        MFMA_V(d3, aB, bB);
        if (u < 15) {                          // prefetch under the MFMAs
            bA = sb[(u + 1) * 64];
            bB = sb[(u + 1) * 64 + 32];
        }
#pragma unroll
        for (int r = 0; r < 16; r++)
            acc0[r] = fmaxf(fmaxf(acc0[r], d0[r]), d1[r]);
#pragma unroll
        for (int r = 0; r < 16; r++)
            acc1[r] = fmaxf(fmaxf(acc1[r], d2[r]), d3[r]);
    }

    __syncthreads();   // all waves done reading sbuf before scratch overwrite

    // ---- col-reduce via per-wave LDS transpose (0 conflicts, proven R2-R6) ----
    float* scr = (float*)(ldsraw + wv * 8704);     // 64 rows x 34 floats
#pragma unroll
    for (int r = 0; r < 16; r++) {
        int row = (r & 3) + 8 * (r >> 2) + 4 * hf;
        scr[row * 34 + m]        = acc0[r];
        scr[(row + 32) * 34 + m] = acc1[r];
    }
    __builtin_amdgcn_s_waitcnt(0);   // own-wave LDS writes visible

    const float2* rv = (const float2*)(ldsraw + wv * 8704 + ln * 136);
    float mx = -3.0e38f;
#pragma unroll
    for (int k = 0; k < 16; k += 2) {
        float2 v0 = rv[k], v1 = rv[k + 1];
        mx = fmaxf(fmaxf(mx, fmaxf(v0.x, v0.y)), fmaxf(v1.x, v1.y));
    }
    atomicMax(&mm[rbase + wv * 64 + ln], enc_f(mx));

    // ---- last-block-done: tail computes both losses ----
    __threadfence();                       // drain atomics before signaling
    if (tid == 0) {
        unsigned prev = atomicAdd(done, 1u);
        tailflag = (prev == GRID - 1);
    }
    __syncthreads();
    if (!tailflag) return;
    __threadfence();                       // acquire

    // g=0: n2p (2048 elems, thr^2/2=0.125); g=1: p2p (32768 elems, thr^2/2=0.005)
    float cnt[2] = {0,0}, spos[2] = {0,0}, sneg[2] = {0,0};
    for (int i = tid; i < NPTS; i += TPB) {
        float score; int g;
        if (i < NF)           { score = p2p_ref[i];           g = 1; }
        else if (i < 2*NF)    { score = p2p_src[i - NF];      g = 1; }
        else if (i < 2*NF+NC) { score = n2p_ref[i - 2*NF];    g = 0; }
        else                  { score = n2p_src[i - 2*NF-NC]; g = 0; }
        float maxm = dec_f(atomicMax(&mm[i], 0u));   // coherent read (0 never raises)
        P3 q = q_point(i, refc, srcc, reff, srcf, T);
        float hq = 0.5f*(q.x*q.x + q.y*q.y + q.z*q.z);
        float thr_half = g ? 0.005f : 0.125f;
        if (maxm > (hq - thr_half)) { cnt[g] += 1.0f; spos[g] -= logf(score); }
        else                        { sneg[g] -= log1pf(-score); }
    }
#pragma unroll
    for (int off = 32; off > 0; off >>= 1) {
#pragma unroll
        for (int g = 0; g < 2; g++) {
            cnt[g]  += __shfl_down(cnt[g],  off, 64);
            spos[g] += __shfl_down(spos[g], off, 64);
            sneg[g] += __shfl_down(sneg[g], off, 64);
        }
    }
    if (ln == 0) {
#pragma unroll
        for (int g = 0; g < 2; g++) { rc[g][wv]=cnt[g]; rp[g][wv]=spos[g]; rn[g][wv]=sneg[g]; }
    }
    __syncthreads();
    if (tid == 0) {
#pragma unroll
        for (int g = 0; g < 2; g++) {
            float c=0, sp=0, sn=0;
            for (int w = 0; w < 4; w++) { c += rc[g][w]; sp += rp[g][w]; sn += rn[g][w]; }
            float N = g ? (float)(2*NF) : (float)(2*NC);
            float wneg = c / N, wpos = 1.0f - wneg;
            out[g] = (wpos * sp + wneg * sn) / N;    // out[0]=n2p, out[1]=p2p
        }
    }
}

extern "C" void kernel_launch(void* const* d_in, const int* in_sizes, int n_in,
                              void* d_out, int out_size, void* d_ws, size_t ws_size,
                              hipStream_t stream) {
    (void)in_sizes; (void)n_in; (void)out_size; (void)ws_size;
    const float* refc = (const float*)d_in[0];
    const float* srcc = (const float*)d_in[1];
    const float* reff = (const float*)d_in[2];
    const float* srcf = (const float*)d_in[3];
    const float* T    = (const float*)d_in[4];
    const float* p2p_ref = (const float*)d_in[5];
    const float* p2p_src = (const float*)d_in[6];
    const float* n2p_ref = (const float*)d_in[7];
    const float* n2p_src = (const float*)d_in[8];
    float* out = (float*)d_out;

    unsigned* mm   = (unsigned*)d_ws;          // [NPTS] encoded maxes
    unsigned* done = mm + NPTS;                // [1] block-done counter

    hipMemsetAsync(mm, 0, (NPTS + 1) * sizeof(unsigned), stream);
    minmax_kernel<<<GRID, TPB, 0, stream>>>(
        refc, srcc, reff, srcf, T, p2p_ref, p2p_src, n2p_ref, n2p_src,
        mm, done, out);
}

// Round 8
// 125.983 us; speedup vs baseline: 2.4232x; 2.4232x over previous
//
#include <hip/hip_runtime.h>
#include <math.h>

#define NC 1024
#define NF 16384
#define NPTS (2*NF + 2*NC)   // 34816 packed points / max-accumulators
#define TPB  256

typedef _Float16 f16x8 __attribute__((ext_vector_type(8)));
typedef float    f32x16 __attribute__((ext_vector_type(16)));

// Order-preserving float -> uint encoding (for atomicMax on floats incl. negatives)
__device__ __forceinline__ unsigned enc_f(float f) {
    unsigned u = __float_as_uint(f);
    return (u & 0x80000000u) ? ~u : (u | 0x80000000u);
}
__device__ __forceinline__ float dec_f(unsigned k) {
    unsigned u = (k & 0x80000000u) ? (k ^ 0x80000000u) : ~k;
    return __uint_as_float(u);
}

// VGPR-form MFMA via inline asm: guarantees D in arch VGPRs (the builtin parks
// D/acc in AGPRs -> per-iter v_accvgpr traffic; R3-R5 evidence). Literal 0 C.
#define MFMA_V(d, a, b) \
    asm("v_mfma_f32_32x32x16_f16 %0, %1, %2, 0" : "=&v"(d) : "v"(a), "v"(b))

// Packed point-index layout (recs, hq, mm all share it):
//   [0, NF)            : ref_points_f             (pass A queries; B/D targets)
//   [NF, 2NF)          : src_points_f transformed (pass B queries; A/C targets)
//   [2NF, 2NF+NC)      : ref_points_c             (pass C queries)
//   [2NF+NC, 2NF+2NC)  : src_points_c transformed (pass D queries)
//
// f16 hi/lo split records for MFMA K-packing (K=16):
//   Q rec: k = [qhx qhy qhz | qlx qly qlz | qhx qhy qhz | 1 1 | qlx qly qlz | 0 0]
//   T rec: k = [phx phy phz | phx phy phz | plx ply plz | -hh -hl | plx ply plz | 0 0]
// => sum_k Q[k]T[k] = q.p - |p|^2/2  (residual ~1e-5); verified absmax 0 (R2-R7).
__global__ __launch_bounds__(TPB) void prep_kernel(
    const float* __restrict__ refc, const float* __restrict__ srcc,
    const float* __restrict__ reff, const float* __restrict__ srcf,
    const float* __restrict__ T,
    f16x8* __restrict__ a0, f16x8* __restrict__ a1,
    f16x8* __restrict__ b0, f16x8* __restrict__ b1,
    float* __restrict__ hqv, unsigned* __restrict__ mm)
{
    int i = blockIdx.x * blockDim.x + threadIdx.x;
    if (i >= NPTS) return;
    mm[i] = 0u;  // below every encoded float
    float x, y, z;
    bool xform;
    if (i < NF) {
        const float* p = reff + 3*i;             x=p[0]; y=p[1]; z=p[2]; xform=false;
    } else if (i < 2*NF) {
        const float* p = srcf + 3*(i - NF);      x=p[0]; y=p[1]; z=p[2]; xform=true;
    } else if (i < 2*NF + NC) {
        const float* p = refc + 3*(i - 2*NF);    x=p[0]; y=p[1]; z=p[2]; xform=false;
    } else {
        const float* p = srcc + 3*(i - 2*NF-NC); x=p[0]; y=p[1]; z=p[2]; xform=true;
    }
    if (xform) {
        float nx = T[0]*x + T[1]*y + T[2]*z  + T[3];
        float ny = T[4]*x + T[5]*y + T[6]*z  + T[7];
        float nz = T[8]*x + T[9]*y + T[10]*z + T[11];
        x = nx; y = ny; z = nz;
    }
    float h = 0.5f*(x*x + y*y + z*z);
    hqv[i] = h;
    _Float16 hx = (_Float16)x; _Float16 hy = (_Float16)y; _Float16 hz = (_Float16)z;
    _Float16 lx = (_Float16)(x - (float)hx);
    _Float16 ly = (_Float16)(y - (float)hy);
    _Float16 lz = (_Float16)(z - (float)hz);
    _Float16 hh = (_Float16)h;
    _Float16 hl = (_Float16)(h - (float)hh);
    _Float16 one = (_Float16)1.0f, zz = (_Float16)0.0f;
    a0[i] = (f16x8){hx, hy, hz, lx, ly, lz, hx, hy};
    a1[i] = (f16x8){hz, one, one, lx, ly, lz, zz, zz};
    b0[i] = (f16x8){hx, hy, hz, hx, hy, hz, lx, ly};
    b1[i] = (f16x8){lz, (_Float16)(-hh), (_Float16)(-hl), lx, ly, lz, zz, zz};
}

// MFMA min-distance kernel, swapped-operand form.
// Block = 256 query rows x 1024 targets; wave w owns queries [w*64, w*64+64)
// as two 32-col fragments (aA, aB used as the MFMA *B* operand). Target
// records stream from LDS as the MFMA *A* operand (same ds_read pattern).
// D(col=query, row=target) => max-over-targets is an IN-LANE reduce of the
// 16 D regs: no epilogue transpose, no LDS scratch, no 2nd barrier.
// 4 running max-chains (acc0e/o, acc1e/o) give 4-way ILP; 32 v_max3 per iter.
// Grid 2176:
//   A [0,1024):     rb in [0,64) x ck in [0,16)  Q=ref_f    T=src_f_t
//   B [1024,2048):  same shape                    Q=src_f_t  T=ref_f
//   C [2048,2112):  rb in [0,4)  x ck in [0,16)  Q=ref_c    T=src_f_t
//   D [2112,2176):  same shape                    Q=src_c_t  T=ref_f
__global__ __launch_bounds__(TPB, 4) void minmax_kernel(
    const f16x8* __restrict__ a0g, const f16x8* __restrict__ a1g,
    const f16x8* __restrict__ b0g, const f16x8* __restrict__ b1g,
    unsigned* __restrict__ mm)
{
    __shared__ __align__(16) f16x8 sbuf[2048];   // exactly 32 KB

    int b = blockIdx.x;
    int qoff, toff, rb, ck;
    if (b < 1024)      { rb = b >> 4;              ck = b & 15; qoff = 0;          toff = NF; }
    else if (b < 2048) { int bb=b-1024; rb=bb>>4;  ck=bb&15;    qoff = NF;         toff = 0;  }
    else if (b < 2112) { int bb=b-2048; rb=bb>>4;  ck=bb&15;    qoff = 2*NF;       toff = NF; }
    else               { int bb=b-2112; rb=bb>>4;  ck=bb&15;    qoff = 2*NF + NC;  toff = 0;  }
    int rbase = qoff + rb * 256;
    int tbase = toff + ck * 1024;

    int tid = threadIdx.x, wv = tid >> 6, ln = tid & 63;

    // stage 2048 target records (16B/lane, coalesced dwordx4)
#pragma unroll
    for (int k = 0; k < 8; k++) {
        int i = tid + k * 256;
        sbuf[i] = (i < 1024) ? b0g[tbase + i] : b1g[tbase + i - 1024];
    }

    int m  = ln & 31;        // query col within tile / target row within tile
    int hf = ln >> 5;        // K-group select
    int rA = rbase + wv * 64 + m;
    f16x8 aA = hf ? a1g[rA]      : a0g[rA];        // queries [wv*64, wv*64+32)
    f16x8 aB = hf ? a1g[rA + 32] : a0g[rA + 32];   // queries [wv*64+32, +64)

    float a0e = -3.0e38f, a0o = -3.0e38f, a1e = -3.0e38f, a1o = -3.0e38f;

    __syncthreads();

    const f16x8* sb = sbuf + hf * 1024 + m;
    f16x8 bA = sb[0], bB = sb[32];
    for (int u = 0; u < 16; ++u) {            // 2 target-tiles (64 targets)/iter
        f32x16 d0, d1, d2, d3;
        MFMA_V(d0, bA, aA);    // targets as rows, queries as cols
        MFMA_V(d1, bA, aB);
        MFMA_V(d2, bB, aA);
        MFMA_V(d3, bB, aB);
        if (u < 15) {                          // prefetch under the MFMAs
            bA = sb[(u + 1) * 64];
            bB = sb[(u + 1) * 64 + 32];
        }
        // in-lane retire: 4 independent max3-chains (even/odd per query frag)
#pragma unroll
        for (int r = 0; r < 16; r += 4) {
            a0e = fmaxf(fmaxf(a0e, d0[r]),     d0[r+2]);   // v_max3
            a0o = fmaxf(fmaxf(a0o, d0[r+1]),   d0[r+3]);
            a1e = fmaxf(fmaxf(a1e, d1[r]),     d1[r+2]);
            a1o = fmaxf(fmaxf(a1o, d1[r+1]),   d1[r+3]);
        }
#pragma unroll
        for (int r = 0; r < 16; r += 4) {
            a0e = fmaxf(fmaxf(a0e, d2[r]),     d2[r+2]);
            a0o = fmaxf(fmaxf(a0o, d2[r+1]),   d2[r+3]);
            a1e = fmaxf(fmaxf(a1e, d3[r]),     d3[r+2]);
            a1o = fmaxf(fmaxf(a1o, d3[r+1]),   d3[r+3]);
        }
    }

    // epilogue: fold chains, combine hf halves (rows split across lane>>5),
    // then one atomicMax per query. No LDS, no barrier.
    float o0 = fmaxf(a0e, a0o);
    float o1 = fmaxf(a1e, a1o);
    o0 = fmaxf(o0, __shfl_xor(o0, 32, 64));
    o1 = fmaxf(o1, __shfl_xor(o1, 32, 64));
    if (ln < 32) {
        atomicMax(&mm[rbase + wv * 64 + ln],      enc_f(o0));
        atomicMax(&mm[rbase + wv * 64 + 32 + ln], enc_f(o1));
    }
}

// Block 0: n2p loss (2048 elems, thr=0.5). Block 1: p2p loss (32768 elems, thr=0.1).
__global__ __launch_bounds__(1024) void loss_kernel(
    const float* __restrict__ hqv, const unsigned* __restrict__ mm,
    const float* __restrict__ p2p_ref, const float* __restrict__ p2p_src,
    const float* __restrict__ n2p_ref, const float* __restrict__ n2p_src,
    float* __restrict__ out)
{
    __shared__ float rc[16], rp[16], rn[16];
    bool is_p2p = (blockIdx.x == 1);
    int N = is_p2p ? 2*NF : 2*NC;
    float thr_half = is_p2p ? 0.5f*(0.1f*0.1f) : 0.5f*(0.5f*0.5f);

    float cnt = 0.0f, spos = 0.0f, sneg = 0.0f;
    for (int i = threadIdx.x; i < N; i += 1024) {
        float score; int qi;
        if (is_p2p) {
            if (i < NF) { score = p2p_src[i];      qi = NF + i; }           // src_gt: pass B
            else        { score = p2p_ref[i - NF]; qi = i - NF; }           // ref_gt: pass A
        } else {
            if (i < NC) { score = n2p_src[i];      qi = 2*NF + NC + i; }    // src_gt_n: pass D
            else        { score = n2p_ref[i - NC]; qi = 2*NF + (i - NC); }  // ref_gt_n: pass C
        }
        float maxm = dec_f(mm[qi]);
        float hq = hqv[qi];            // |q|^2 / 2 (fp32 exact)
        bool g = maxm > (hq - thr_half);
        if (g) { cnt += 1.0f; spos -= logf(score); }
        else   { sneg -= log1pf(-score); }
    }

    int lane = threadIdx.x & 63, wid = threadIdx.x >> 6;
#pragma unroll
    for (int off = 32; off > 0; off >>= 1) {
        cnt  += __shfl_down(cnt,  off, 64);
        spos += __shfl_down(spos, off, 64);
        sneg += __shfl_down(sneg, off, 64);
    }
    if (lane == 0) { rc[wid] = cnt; rp[wid] = spos; rn[wid] = sneg; }
    __syncthreads();
    if (threadIdx.x == 0) {
        float c = 0, sp = 0, sn = 0;
        for (int w = 0; w < 16; w++) { c += rc[w]; sp += rp[w]; sn += rn[w]; }
        float wneg = c / (float)N;
        float wpos = 1.0f - wneg;
        out[blockIdx.x] = (wpos * sp + wneg * sn) / (float)N;   // out[0]=n2p, out[1]=p2p
    }
}

extern "C" void kernel_launch(void* const* d_in, const int* in_sizes, int n_in,
                              void* d_out, int out_size, void* d_ws, size_t ws_size,
                              hipStream_t stream) {
    (void)in_sizes; (void)n_in; (void)out_size; (void)ws_size;
    const float* refc = (const float*)d_in[0];
    const float* srcc = (const float*)d_in[1];
    const float* reff = (const float*)d_in[2];
    const float* srcf = (const float*)d_in[3];
    const float* T    = (const float*)d_in[4];
    const float* p2p_ref = (const float*)d_in[5];
    const float* p2p_src = (const float*)d_in[6];
    const float* n2p_ref = (const float*)d_in[7];
    const float* n2p_src = (const float*)d_in[8];
    float* out = (float*)d_out;

    f16x8* a0 = (f16x8*)d_ws;
    f16x8* a1 = a0 + NPTS;
    f16x8* b0 = a1 + NPTS;
    f16x8* b1 = b0 + NPTS;
    float* hqv = (float*)(b1 + NPTS);
    unsigned* mm = (unsigned*)(hqv + NPTS);   // total ws use: 72*NPTS = ~2.5 MB

    prep_kernel<<<(NPTS + TPB - 1) / TPB, TPB, 0, stream>>>(
        refc, srcc, reff, srcf, T, a0, a1, b0, b1, hqv, mm);
    minmax_kernel<<<2176, TPB, 0, stream>>>(a0, a1, b0, b1, mm);
    loss_kernel<<<2, 1024, 0, stream>>>(hqv, mm, p2p_ref, p2p_src, n2p_ref, n2p_src, out);
}